// Round 1
// baseline (1103.558 us; speedup 1.0000x reference)
//
#include <hip/hip_runtime.h>
#include <math.h>

#define NCH 96   // HID_C == OUT_C == 96

// ---------------------------------------------------------------------------
// init: deg = 1.0 (self-loop), zero the small stats/pool region
// ---------------------------------------------------------------------------
__global__ void init_kernel(float* __restrict__ deg, float* __restrict__ small,
                            int n, int nsmall) {
    int i = blockIdx.x * blockDim.x + threadIdx.x;
    if (i < n) deg[i] = 1.0f;
    if (i < nsmall) small[i] = 0.0f;
}

__global__ void deg_kernel(const int* __restrict__ dst, float* __restrict__ deg, int E) {
    int e = blockIdx.x * blockDim.x + threadIdx.x;
    if (e < E) atomicAdd(&deg[dst[e]], 1.0f);
}

__global__ void dinv_kernel(float* __restrict__ deg, int n) {
    int i = blockIdx.x * blockDim.x + threadIdx.x;
    if (i < n) deg[i] = rsqrtf(deg[i]);   // in-place: deg buffer becomes dinv
}

// ---------------------------------------------------------------------------
// GEMM: hs[r][c] = (x[r][:] @ W[:][c]) * dinv[r]; also pre-init acc = hs
// (self-loop term). Block = (32,8) threads, 32 rows per block, W in LDS,
// x staged in 32-wide K chunks. Thread (c0,ry) computes rows {ry+8j} and
// cols {c0+32i}. W reads coalesced (lanes 0..31 consecutive); X reads are
// 2-way bank-aliased (free on CDNA4).
// ---------------------------------------------------------------------------
template <int K>
__global__ __launch_bounds__(256) void gemm_hs(const float* __restrict__ x,
                                               const float* __restrict__ W,
                                               const float* __restrict__ dinv,
                                               float* __restrict__ hs,
                                               float* __restrict__ acc, int n) {
    __shared__ float Wl[K * NCH];
    __shared__ float Xl[32 * 32];
    const int tid = threadIdx.y * 32 + threadIdx.x;
    for (int i = tid; i < K * NCH; i += 256) Wl[i] = W[i];

    const int r0 = blockIdx.x * 32;
    const int c0 = threadIdx.x;   // 0..31
    const int ry = threadIdx.y;   // 0..7
    float a[4][3] = {};

    for (int kc = 0; kc < K; kc += 32) {
        __syncthreads();  // first iter: covers W load; later: protect Xl reuse
        for (int i = tid; i < 32 * 32; i += 256) {
            int row = i >> 5, kk = i & 31;
            int r = r0 + row;
            Xl[i] = (r < n) ? x[(size_t)r * K + kc + kk] : 0.0f;
        }
        __syncthreads();
#pragma unroll
        for (int kk = 0; kk < 32; ++kk) {
            float w0 = Wl[(kc + kk) * NCH + c0];
            float w1 = Wl[(kc + kk) * NCH + c0 + 32];
            float w2 = Wl[(kc + kk) * NCH + c0 + 64];
#pragma unroll
            for (int j = 0; j < 4; ++j) {
                float xv = Xl[(ry + 8 * j) * 32 + kk];
                a[j][0] = fmaf(xv, w0, a[j][0]);
                a[j][1] = fmaf(xv, w1, a[j][1]);
                a[j][2] = fmaf(xv, w2, a[j][2]);
            }
        }
    }

#pragma unroll
    for (int j = 0; j < 4; ++j) {
        int r = r0 + ry + 8 * j;
        if (r < n) {
            float dv = dinv[r];
#pragma unroll
            for (int i2 = 0; i2 < 3; ++i2) {
                float v = a[j][i2] * dv;
                size_t idx = (size_t)r * NCH + c0 + 32 * i2;
                hs[idx] = v;
                acc[idx] = v;  // init accumulator with self-loop term
            }
        }
    }
}

// ---------------------------------------------------------------------------
// scatter: acc[dst] += hs[src], 32 lanes per edge (3 channels each)
// ---------------------------------------------------------------------------
__global__ __launch_bounds__(256) void scatter_kernel(const int* __restrict__ ei,
                                                      const float* __restrict__ hs,
                                                      float* __restrict__ acc, int E) {
    int lane = threadIdx.x & 31;
    int e = blockIdx.x * 8 + (threadIdx.x >> 5);
    if (e >= E) return;
    int s = ei[e];
    int d = ei[E + e];
    size_t bs = (size_t)s * NCH;
    size_t bd = (size_t)d * NCH;
    atomicAdd(&acc[bd + lane],      hs[bs + lane]);
    atomicAdd(&acc[bd + lane + 32], hs[bs + lane + 32]);
    atomicAdd(&acc[bd + lane + 64], hs[bs + lane + 64]);
}

// ---------------------------------------------------------------------------
// BN column stats of t = acc*dinv  (sum, sumsq). Block = (96,4).
// ---------------------------------------------------------------------------
__global__ __launch_bounds__(384) void stats_kernel(const float* __restrict__ acc,
                                                    const float* __restrict__ dinv,
                                                    float* __restrict__ sums, int n) {
    int c = threadIdx.x;   // 0..95
    int ry = threadIdx.y;  // 0..3
    float s1 = 0.f, s2 = 0.f;
    for (int r = blockIdx.x * 4 + ry; r < n; r += gridDim.x * 4) {
        float t = acc[(size_t)r * NCH + c] * dinv[r];
        s1 += t;
        s2 = fmaf(t, t, s2);
    }
    __shared__ float L1[4][NCH], L2[4][NCH];
    L1[ry][c] = s1;
    L2[ry][c] = s2;
    __syncthreads();
    if (ry == 0) {
        s1 = L1[0][c] + L1[1][c] + L1[2][c] + L1[3][c];
        s2 = L2[0][c] + L2[1][c] + L2[2][c] + L2[3][c];
        atomicAdd(&sums[c], s1);
        atomicAdd(&sums[NCH + c], s2);
    }
}

// a = g*rsqrt(var+eps); shift = bt - mean*a  (one tiny block)
__global__ void bnparam_kernel(const float* __restrict__ sums,
                               const float* __restrict__ g,
                               const float* __restrict__ bt,
                               float* __restrict__ ab, float n) {
    int c = threadIdx.x;
    if (c < NCH) {
        float mean = sums[c] / n;
        float var = sums[NCH + c] / n - mean * mean;
        float a = g[c] * rsqrtf(var + 1e-5f);
        ab[c] = a;
        ab[NCH + c] = bt[c] - mean * a;
    }
}

// y = relu((acc*dinv)*a + shift)
__global__ __launch_bounds__(384) void apply_kernel(const float* __restrict__ acc,
                                                    const float* __restrict__ dinv,
                                                    const float* __restrict__ ab,
                                                    float* __restrict__ y, int n) {
    int c = threadIdx.x, ry = threadIdx.y;
    float a = ab[c], b = ab[NCH + c];
    for (int r = blockIdx.x * 4 + ry; r < n; r += gridDim.x * 4) {
        float t = acc[(size_t)r * NCH + c] * dinv[r];
        y[(size_t)r * NCH + c] = fmaxf(fmaf(t, a, b), 0.f);
    }
}

// column sums of final activations -> pool[96]
__global__ __launch_bounds__(384) void pool_kernel(const float* __restrict__ y,
                                                   float* __restrict__ pool, int n) {
    int c = threadIdx.x, ry = threadIdx.y;
    float s = 0.f;
    for (int r = blockIdx.x * 4 + ry; r < n; r += gridDim.x * 4)
        s += y[(size_t)r * NCH + c];
    __shared__ float L[4][NCH];
    L[ry][c] = s;
    __syncthreads();
    if (ry == 0) atomicAdd(&pool[c], L[0][c] + L[1][c] + L[2][c] + L[3][c]);
}

// tiny MLP head: 96 -> 128 -> 64 -> 32 -> 1, one block of 128 threads
__global__ __launch_bounds__(128) void mlp_kernel(const float* __restrict__ pool,
        const float* __restrict__ fw1, const float* __restrict__ fb1,
        const float* __restrict__ fw2, const float* __restrict__ fb2,
        const float* __restrict__ fw3, const float* __restrict__ fb3,
        const float* __restrict__ fw4, const float* __restrict__ fb4,
        float* __restrict__ out, float invn) {
    __shared__ float v[NCH], l1[128], l2[64], l3[32];
    int t = threadIdx.x;
    if (t < NCH) v[t] = pool[t] * invn;
    __syncthreads();
    {
        float a = fb1[t];
        for (int k = 0; k < NCH; ++k) a = fmaf(v[k], fw1[k * 128 + t], a);
        l1[t] = fmaxf(a, 0.f);
    }
    __syncthreads();
    if (t < 64) {
        float a = fb2[t];
        for (int k = 0; k < 128; ++k) a = fmaf(l1[k], fw2[k * 64 + t], a);
        l2[t] = fmaxf(a, 0.f);
    }
    __syncthreads();
    if (t < 32) {
        float a = fb3[t];
        for (int k = 0; k < 64; ++k) a = fmaf(l2[k], fw3[k * 32 + t], a);
        l3[t] = fmaxf(a, 0.f);
    }
    __syncthreads();
    if (t == 0) {
        float a = fb4[0];
        for (int k = 0; k < 32; ++k) a = fmaf(l3[k], fw4[k], a);
        out[0] = a;
    }
}

// ---------------------------------------------------------------------------
extern "C" void kernel_launch(void* const* d_in, const int* in_sizes, int n_in,
                              void* d_out, int out_size, void* d_ws, size_t ws_size,
                              hipStream_t stream) {
    const float* x  = (const float*)d_in[0];
    const int*  ei  = (const int*)d_in[1];
    const float* W1 = (const float*)d_in[2];
    // d_in[3] = b1: cancels in BatchNorm (mean subtraction) — unused
    const float* W2 = (const float*)d_in[4];
    const float* W3 = (const float*)d_in[6];
    const float* g1 = (const float*)d_in[8],  *bt1 = (const float*)d_in[9];
    const float* g2 = (const float*)d_in[10], *bt2 = (const float*)d_in[11];
    const float* g3 = (const float*)d_in[12], *bt3 = (const float*)d_in[13];
    const float* fw1 = (const float*)d_in[14], *fb1 = (const float*)d_in[15];
    const float* fw2 = (const float*)d_in[16], *fb2 = (const float*)d_in[17];
    const float* fw3 = (const float*)d_in[18], *fb3 = (const float*)d_in[19];
    const float* fw4 = (const float*)d_in[20], *fb4 = (const float*)d_in[21];
    float* out = (float*)d_out;

    const int N = in_sizes[0] / 128;
    const int E = in_sizes[1] / 2;
    const size_t n96 = (size_t)N * NCH;

    float* ws    = (float*)d_ws;
    float* P     = ws;              // hs / ping          N*96
    float* Q     = P + n96;         // activations / pong N*96
    float* ACC   = Q + n96;         // aggregation acc    N*96
    float* dinv  = ACC + n96;       // N  (deg -> dinv in place)
    float* sums1 = dinv + N;        // 192
    float* sums2 = sums1 + 2 * NCH; // 192
    float* sums3 = sums2 + 2 * NCH; // 192
    float* pool  = sums3 + 2 * NCH; // 96
    float* ab1   = pool + NCH;      // 192
    float* ab2   = ab1 + 2 * NCH;   // 192
    float* ab3   = ab2 + 2 * NCH;   // 192
    const int nsmall = 3 * 2 * NCH + NCH;  // sums1..3 + pool

    dim3 b96(NCH, 4);

    // degree / dinv
    init_kernel<<<(N + 255) / 256, 256, 0, stream>>>(dinv, sums1, N, nsmall);
    deg_kernel<<<(E + 255) / 256, 256, 0, stream>>>(ei + E, dinv, E);
    dinv_kernel<<<(N + 255) / 256, 256, 0, stream>>>(dinv, N);

    const int gemmGrid = (N + 31) / 32;
    const int scatGrid = (E + 7) / 8;

    // ---- layer 1: x(128) -> 96 ----
    gemm_hs<128><<<gemmGrid, dim3(32, 8), 0, stream>>>(x, W1, dinv, P, ACC, N);
    scatter_kernel<<<scatGrid, 256, 0, stream>>>(ei, P, ACC, E);
    stats_kernel<<<512, b96, 0, stream>>>(ACC, dinv, sums1, N);
    bnparam_kernel<<<1, NCH, 0, stream>>>(sums1, g1, bt1, ab1, (float)N);
    apply_kernel<<<768, b96, 0, stream>>>(ACC, dinv, ab1, Q, N);

    // ---- layer 2: 96 -> 96 ----
    gemm_hs<96><<<gemmGrid, dim3(32, 8), 0, stream>>>(Q, W2, dinv, P, ACC, N);
    scatter_kernel<<<scatGrid, 256, 0, stream>>>(ei, P, ACC, E);
    stats_kernel<<<512, b96, 0, stream>>>(ACC, dinv, sums2, N);
    bnparam_kernel<<<1, NCH, 0, stream>>>(sums2, g2, bt2, ab2, (float)N);
    apply_kernel<<<768, b96, 0, stream>>>(ACC, dinv, ab2, P, N);

    // ---- layer 3: 96 -> 96 ----
    gemm_hs<96><<<gemmGrid, dim3(32, 8), 0, stream>>>(P, W3, dinv, Q, ACC, N);
    scatter_kernel<<<scatGrid, 256, 0, stream>>>(ei, Q, ACC, E);
    stats_kernel<<<512, b96, 0, stream>>>(ACC, dinv, sums3, N);
    bnparam_kernel<<<1, NCH, 0, stream>>>(sums3, g3, bt3, ab3, (float)N);
    apply_kernel<<<768, b96, 0, stream>>>(ACC, dinv, ab3, Q, N);

    // ---- pool + MLP head ----
    pool_kernel<<<512, b96, 0, stream>>>(Q, pool, N);
    mlp_kernel<<<1, 128, 0, stream>>>(pool, fw1, fb1, fw2, fb2, fw3, fb3,
                                      fw4, fb4, out, 1.0f / (float)N);
}

// Round 2
// 710.889 us; speedup vs baseline: 1.5524x; 1.5524x over previous
//
#include <hip/hip_runtime.h>
#include <math.h>

#define NCH 96   // HID_C == OUT_C == 96

// ---------------------------------------------------------------------------
// zero: cnt[] = 0, small stats/pool region = 0
// ---------------------------------------------------------------------------
__global__ void zero_kernel(int* __restrict__ cnt, float* __restrict__ small,
                            int n, int nsmall) {
    int i = blockIdx.x * blockDim.x + threadIdx.x;
    if (i < n) cnt[i] = 0;
    if (i < nsmall) small[i] = 0.0f;
}

// in-degree count (int atomics, L2-resident 200 KB counter array)
__global__ void count_kernel(const int* __restrict__ dst, int* __restrict__ cnt, int E) {
    int e = blockIdx.x * blockDim.x + threadIdx.x;
    if (e < E) atomicAdd(&cnt[dst[e]], 1);
}

// single-block exclusive scan over cnt -> rowptr; cnt becomes fill cursor;
// also dinv = rsqrt(deg+1)
__global__ __launch_bounds__(1024) void scan_kernel(int* __restrict__ cnt,
                                                    int* __restrict__ rowptr,
                                                    float* __restrict__ dinv, int n) {
    __shared__ int ps[1024];
    int t = threadIdx.x;
    int chunk = (n + 1023) >> 10;
    int lo = t * chunk, hi = min(lo + chunk, n);
    int s = 0;
    for (int i = lo; i < hi; ++i) s += cnt[i];
    ps[t] = s;
    __syncthreads();
    for (int off = 1; off < 1024; off <<= 1) {
        int add = (t >= off) ? ps[t - off] : 0;
        __syncthreads();
        ps[t] += add;
        __syncthreads();
    }
    int run = ps[t] - s;   // exclusive prefix of this thread's chunk
    for (int i = lo; i < hi; ++i) {
        int c = cnt[i];
        rowptr[i] = run;
        cnt[i] = run;                       // reuse cnt as fill cursor
        dinv[i] = rsqrtf((float)(c + 1));   // self-loop degree
        run += c;
    }
    if (t == 1023) rowptr[n] = ps[1023];
}

// adj fill via int atomics on the fill cursors
__global__ void fill_kernel(const int* __restrict__ ei, int* __restrict__ fill,
                            int* __restrict__ adj, int E) {
    int e = blockIdx.x * blockDim.x + threadIdx.x;
    if (e < E) {
        int s = ei[e];
        int pos = atomicAdd(&fill[ei[E + e]], 1);
        adj[pos] = s;
    }
}

// ---------------------------------------------------------------------------
// GEMM: hs[r][c] = (x[r][:] @ W[:][c]) * dinv[r]
// ---------------------------------------------------------------------------
template <int K>
__global__ __launch_bounds__(256) void gemm_hs(const float* __restrict__ x,
                                               const float* __restrict__ W,
                                               const float* __restrict__ dinv,
                                               float* __restrict__ hs, int n) {
    __shared__ float Wl[K * NCH];
    __shared__ float Xl[32 * 32];
    const int tid = threadIdx.y * 32 + threadIdx.x;
    for (int i = tid; i < K * NCH; i += 256) Wl[i] = W[i];

    const int r0 = blockIdx.x * 32;
    const int c0 = threadIdx.x;   // 0..31
    const int ry = threadIdx.y;   // 0..7
    float a[4][3] = {};

    for (int kc = 0; kc < K; kc += 32) {
        __syncthreads();
        for (int i = tid; i < 32 * 32; i += 256) {
            int row = i >> 5, kk = i & 31;
            int r = r0 + row;
            Xl[i] = (r < n) ? x[(size_t)r * K + kc + kk] : 0.0f;
        }
        __syncthreads();
#pragma unroll
        for (int kk = 0; kk < 32; ++kk) {
            float w0 = Wl[(kc + kk) * NCH + c0];
            float w1 = Wl[(kc + kk) * NCH + c0 + 32];
            float w2 = Wl[(kc + kk) * NCH + c0 + 64];
#pragma unroll
            for (int j = 0; j < 4; ++j) {
                float xv = Xl[(ry + 8 * j) * 32 + kk];
                a[j][0] = fmaf(xv, w0, a[j][0]);
                a[j][1] = fmaf(xv, w1, a[j][1]);
                a[j][2] = fmaf(xv, w2, a[j][2]);
            }
        }
    }

#pragma unroll
    for (int j = 0; j < 4; ++j) {
        int r = r0 + ry + 8 * j;
        if (r < n) {
            float dv = dinv[r];
#pragma unroll
            for (int i2 = 0; i2 < 3; ++i2)
                hs[(size_t)r * NCH + c0 + 32 * i2] = a[j][i2] * dv;
        }
    }
}

// ---------------------------------------------------------------------------
// gather aggregation: t[i] = dinv[i] * (hs[i] + sum_{src in adj[i]} hs[src])
// one wave per node, lanes 0..23 hold float4 each (96 channels)
// ---------------------------------------------------------------------------
__global__ __launch_bounds__(256) void gather_kernel(const int* __restrict__ rowptr,
                                                     const int* __restrict__ adj,
                                                     const float* __restrict__ dinv,
                                                     const float4* __restrict__ HS,
                                                     float4* __restrict__ AGG, int n) {
    int wid = (blockIdx.x * 256 + threadIdx.x) >> 6;
    int lane = threadIdx.x & 63;
    if (wid >= n || lane >= 24) return;
    int lo = rowptr[wid], hi = rowptr[wid + 1];
    float dv = dinv[wid];
    size_t l = lane;

    float4 a = HS[(size_t)wid * 24 + l];   // self term
    float4 b = make_float4(0.f, 0.f, 0.f, 0.f);
    int j = lo;
    for (; j + 1 < hi; j += 2) {
        int s0 = adj[j], s1 = adj[j + 1];
        float4 v0 = HS[(size_t)s0 * 24 + l];
        float4 v1 = HS[(size_t)s1 * 24 + l];
        a.x += v0.x; a.y += v0.y; a.z += v0.z; a.w += v0.w;
        b.x += v1.x; b.y += v1.y; b.z += v1.z; b.w += v1.w;
    }
    if (j < hi) {
        int s0 = adj[j];
        float4 v0 = HS[(size_t)s0 * 24 + l];
        a.x += v0.x; a.y += v0.y; a.z += v0.z; a.w += v0.w;
    }
    a.x = (a.x + b.x) * dv;
    a.y = (a.y + b.y) * dv;
    a.z = (a.z + b.z) * dv;
    a.w = (a.w + b.w) * dv;
    AGG[(size_t)wid * 24 + l] = a;
}

// ---------------------------------------------------------------------------
// BN column stats of t (already dinv-scaled): sum, sumsq. Block = (96,4).
// ---------------------------------------------------------------------------
__global__ __launch_bounds__(384) void stats_kernel(const float* __restrict__ t,
                                                    float* __restrict__ sums, int n) {
    int c = threadIdx.x;   // 0..95
    int ry = threadIdx.y;  // 0..3
    float s1 = 0.f, s2 = 0.f;
    for (int r = blockIdx.x * 4 + ry; r < n; r += gridDim.x * 4) {
        float v = t[(size_t)r * NCH + c];
        s1 += v;
        s2 = fmaf(v, v, s2);
    }
    __shared__ float L1[4][NCH], L2[4][NCH];
    L1[ry][c] = s1;
    L2[ry][c] = s2;
    __syncthreads();
    if (ry == 0) {
        s1 = L1[0][c] + L1[1][c] + L1[2][c] + L1[3][c];
        s2 = L2[0][c] + L2[1][c] + L2[2][c] + L2[3][c];
        atomicAdd(&sums[c], s1);
        atomicAdd(&sums[NCH + c], s2);
    }
}

// a = g*rsqrt(var+eps); shift = bt - mean*a  (one tiny block)
__global__ void bnparam_kernel(const float* __restrict__ sums,
                               const float* __restrict__ g,
                               const float* __restrict__ bt,
                               float* __restrict__ ab, float n) {
    int c = threadIdx.x;
    if (c < NCH) {
        float mean = sums[c] / n;
        float var = sums[NCH + c] / n - mean * mean;
        float a = g[c] * rsqrtf(var + 1e-5f);
        ab[c] = a;
        ab[NCH + c] = bt[c] - mean * a;
    }
}

// y = relu(t*a + shift)
__global__ __launch_bounds__(384) void apply_kernel(const float* __restrict__ t,
                                                    const float* __restrict__ ab,
                                                    float* __restrict__ y, int n) {
    int c = threadIdx.x, ry = threadIdx.y;
    float a = ab[c], b = ab[NCH + c];
    for (int r = blockIdx.x * 4 + ry; r < n; r += gridDim.x * 4) {
        float v = t[(size_t)r * NCH + c];
        y[(size_t)r * NCH + c] = fmaxf(fmaf(v, a, b), 0.f);
    }
}

// column sums of final activations -> pool[96]
__global__ __launch_bounds__(384) void pool_kernel(const float* __restrict__ y,
                                                   float* __restrict__ pool, int n) {
    int c = threadIdx.x, ry = threadIdx.y;
    float s = 0.f;
    for (int r = blockIdx.x * 4 + ry; r < n; r += gridDim.x * 4)
        s += y[(size_t)r * NCH + c];
    __shared__ float L[4][NCH];
    L[ry][c] = s;
    __syncthreads();
    if (ry == 0) atomicAdd(&pool[c], L[0][c] + L[1][c] + L[2][c] + L[3][c]);
}

// tiny MLP head: 96 -> 128 -> 64 -> 32 -> 1, one block of 128 threads
__global__ __launch_bounds__(128) void mlp_kernel(const float* __restrict__ pool,
        const float* __restrict__ fw1, const float* __restrict__ fb1,
        const float* __restrict__ fw2, const float* __restrict__ fb2,
        const float* __restrict__ fw3, const float* __restrict__ fb3,
        const float* __restrict__ fw4, const float* __restrict__ fb4,
        float* __restrict__ out, float invn) {
    __shared__ float v[NCH], l1[128], l2[64], l3[32];
    int t = threadIdx.x;
    if (t < NCH) v[t] = pool[t] * invn;
    __syncthreads();
    {
        float a = fb1[t];
        for (int k = 0; k < NCH; ++k) a = fmaf(v[k], fw1[k * 128 + t], a);
        l1[t] = fmaxf(a, 0.f);
    }
    __syncthreads();
    if (t < 64) {
        float a = fb2[t];
        for (int k = 0; k < 128; ++k) a = fmaf(l1[k], fw2[k * 64 + t], a);
        l2[t] = fmaxf(a, 0.f);
    }
    __syncthreads();
    if (t < 32) {
        float a = fb3[t];
        for (int k = 0; k < 64; ++k) a = fmaf(l2[k], fw3[k * 32 + t], a);
        l3[t] = fmaxf(a, 0.f);
    }
    __syncthreads();
    if (t == 0) {
        float a = fb4[0];
        for (int k = 0; k < 32; ++k) a = fmaf(l3[k], fw4[k], a);
        out[0] = a;
    }
}

// ---------------------------------------------------------------------------
extern "C" void kernel_launch(void* const* d_in, const int* in_sizes, int n_in,
                              void* d_out, int out_size, void* d_ws, size_t ws_size,
                              hipStream_t stream) {
    const float* x  = (const float*)d_in[0];
    const int*  ei  = (const int*)d_in[1];
    const float* W1 = (const float*)d_in[2];
    // b1/b2/b3 cancel in BatchNorm mean subtraction — unused
    const float* W2 = (const float*)d_in[4];
    const float* W3 = (const float*)d_in[6];
    const float* g1 = (const float*)d_in[8],  *bt1 = (const float*)d_in[9];
    const float* g2 = (const float*)d_in[10], *bt2 = (const float*)d_in[11];
    const float* g3 = (const float*)d_in[12], *bt3 = (const float*)d_in[13];
    const float* fw1 = (const float*)d_in[14], *fb1 = (const float*)d_in[15];
    const float* fw2 = (const float*)d_in[16], *fb2 = (const float*)d_in[17];
    const float* fw3 = (const float*)d_in[18], *fb3 = (const float*)d_in[19];
    const float* fw4 = (const float*)d_in[20], *fb4 = (const float*)d_in[21];
    float* out = (float*)d_out;

    const int N = in_sizes[0] / 128;
    const int E = in_sizes[1] / 2;
    const size_t n96 = (size_t)N * NCH;

    // workspace layout
    float* ws    = (float*)d_ws;
    float* B0    = ws;              // ping  N*96
    float* B1    = B0 + n96;        // pong  N*96
    float* dinv  = B1 + n96;        // N
    float* sums1 = dinv + N;        // 192
    float* sums2 = sums1 + 2 * NCH; // 192
    float* sums3 = sums2 + 2 * NCH; // 192
    float* pool  = sums3 + 2 * NCH; // 96
    float* ab1   = pool + NCH;      // 192
    float* ab2   = ab1 + 2 * NCH;   // 192
    float* ab3   = ab2 + 2 * NCH;   // 192
    int*   cnt   = (int*)(ab3 + 2 * NCH);  // N (degree -> fill cursor)
    int*   rowptr= cnt + N;         // N+1
    int*   adj   = rowptr + N + 1;  // E
    const int nsmall = 3 * 2 * NCH + NCH;  // sums1..3 + pool

    dim3 b96(NCH, 4);
    const int gemmGrid = (N + 31) / 32;
    const int gathGrid = (N + 3) / 4;   // 4 waves (nodes) per 256-thread block

    // ---- CSR build + dinv ----
    zero_kernel<<<(N + 255) / 256, 256, 0, stream>>>(cnt, sums1, N, nsmall);
    count_kernel<<<(E + 255) / 256, 256, 0, stream>>>(ei + E, cnt, E);
    scan_kernel<<<1, 1024, 0, stream>>>(cnt, rowptr, dinv, N);
    fill_kernel<<<(E + 255) / 256, 256, 0, stream>>>(ei, cnt, adj, E);

    // ---- layer 1: x(128) -> 96 ----
    gemm_hs<128><<<gemmGrid, dim3(32, 8), 0, stream>>>(x, W1, dinv, B0, N);
    gather_kernel<<<gathGrid, 256, 0, stream>>>(rowptr, adj, dinv,
                                                (const float4*)B0, (float4*)B1, N);
    stats_kernel<<<512, b96, 0, stream>>>(B1, sums1, N);
    bnparam_kernel<<<1, NCH, 0, stream>>>(sums1, g1, bt1, ab1, (float)N);
    apply_kernel<<<768, b96, 0, stream>>>(B1, ab1, B0, N);

    // ---- layer 2: 96 -> 96 ----
    gemm_hs<96><<<gemmGrid, dim3(32, 8), 0, stream>>>(B0, W2, dinv, B1, N);
    gather_kernel<<<gathGrid, 256, 0, stream>>>(rowptr, adj, dinv,
                                                (const float4*)B1, (float4*)B0, N);
    stats_kernel<<<512, b96, 0, stream>>>(B0, sums2, N);
    bnparam_kernel<<<1, NCH, 0, stream>>>(sums2, g2, bt2, ab2, (float)N);
    apply_kernel<<<768, b96, 0, stream>>>(B0, ab2, B1, N);

    // ---- layer 3: 96 -> 96 ----
    gemm_hs<96><<<gemmGrid, dim3(32, 8), 0, stream>>>(B1, W3, dinv, B0, N);
    gather_kernel<<<gathGrid, 256, 0, stream>>>(rowptr, adj, dinv,
                                                (const float4*)B0, (float4*)B1, N);
    stats_kernel<<<512, b96, 0, stream>>>(B1, sums3, N);
    bnparam_kernel<<<1, NCH, 0, stream>>>(sums3, g3, bt3, ab3, (float)N);
    apply_kernel<<<768, b96, 0, stream>>>(B1, ab3, B0, N);

    // ---- pool + MLP head ----
    pool_kernel<<<512, b96, 0, stream>>>(B0, pool, N);
    mlp_kernel<<<1, 128, 0, stream>>>(pool, fw1, fb1, fw2, fb2, fw3, fb3,
                                      fw4, fb4, out, 1.0f / (float)N);
}

// Round 5
// 558.852 us; speedup vs baseline: 1.9747x; 1.2721x over previous
//
#include <hip/hip_runtime.h>
#include <math.h>

#define NCH 96        // HID_C == OUT_C == 96
#define SCAN_TILE 2048  // 256 threads x 8 elements

// ---------------------------------------------------------------------------
// zero: cnt[] = 0, small stats/pool region = 0
// ---------------------------------------------------------------------------
__global__ void zero_kernel(int* __restrict__ cnt, float* __restrict__ small,
                            int n, int nsmall) {
    int i = blockIdx.x * blockDim.x + threadIdx.x;
    if (i < n) cnt[i] = 0;
    if (i < nsmall) small[i] = 0.0f;
}

// in-degree count (int atomics, L2-resident 200 KB counter array)
__global__ void count_kernel(const int* __restrict__ dst, int* __restrict__ cnt, int E) {
    int e = blockIdx.x * blockDim.x + threadIdx.x;
    if (e < E) atomicAdd(&cnt[dst[e]], 1);
}

// ---- multi-block exclusive scan, phase A: per-block sums ----
__global__ __launch_bounds__(256) void scanA_kernel(const int* __restrict__ cnt,
                                                    int* __restrict__ bsum, int n) {
    int b = blockIdx.x, t = threadIdx.x;
    int base = b * SCAN_TILE;
    int s = 0;
    for (int i = t; i < SCAN_TILE; i += 256) {
        int idx = base + i;
        if (idx < n) s += cnt[idx];
    }
#pragma unroll
    for (int off = 32; off; off >>= 1) s += __shfl_down(s, off, 64);
    __shared__ int red[4];
    if ((t & 63) == 0) red[t >> 6] = s;
    __syncthreads();
    if (t == 0) bsum[b] = red[0] + red[1] + red[2] + red[3];
}

// ---- phase B: exclusive scan of block sums (nb <= 256); rowptrN = total ----
__global__ __launch_bounds__(256) void scanB_kernel(int* __restrict__ bsum,
                                                    int* __restrict__ rowptrN, int nb) {
    int t = threadIdx.x;
    __shared__ int ps[256];
    int v = (t < nb) ? bsum[t] : 0;
    ps[t] = v;
    __syncthreads();
    for (int off = 1; off < 256; off <<= 1) {
        int add = (t >= off) ? ps[t - off] : 0;
        __syncthreads();
        ps[t] += add;
        __syncthreads();
    }
    if (t < nb) bsum[t] = ps[t] - v;     // exclusive prefix
    if (t == nb - 1) rowptrN[0] = ps[t]; // total = E
}

// ---- phase C: block-local scan, write rowptr / fill-cursor / dinv ----
__global__ __launch_bounds__(256) void scanC_kernel(int* __restrict__ cnt,
                                                    const int* __restrict__ bsum,
                                                    int* __restrict__ rowptr,
                                                    float* __restrict__ dinv, int n) {
    int b = blockIdx.x, t = threadIdx.x;
    int base = b * SCAN_TILE + t * 8;
    int c[8];
    int s = 0;
#pragma unroll
    for (int j = 0; j < 8; ++j) {
        int idx = base + j;
        c[j] = (idx < n) ? cnt[idx] : 0;
        s += c[j];
    }
    __shared__ int ps[256];
    ps[t] = s;
    __syncthreads();
    for (int off = 1; off < 256; off <<= 1) {
        int add = (t >= off) ? ps[t - off] : 0;
        __syncthreads();
        ps[t] += add;
        __syncthreads();
    }
    int run = bsum[b] + ps[t] - s;
#pragma unroll
    for (int j = 0; j < 8; ++j) {
        int idx = base + j;
        if (idx < n) {
            rowptr[idx] = run;
            cnt[idx] = run;                       // fill cursor
            dinv[idx] = rsqrtf((float)(c[j] + 1)); // self-loop degree
            run += c[j];
        }
    }
}

// adj fill via int atomics on the fill cursors
__global__ void fill_kernel(const int* __restrict__ ei, int* __restrict__ fill,
                            int* __restrict__ adj, int E) {
    int e = blockIdx.x * blockDim.x + threadIdx.x;
    if (e < E) {
        int s = ei[e];
        int pos = atomicAdd(&fill[ei[E + e]], 1);
        adj[pos] = s;
    }
}

// ---------------------------------------------------------------------------
// GEMM: hs[r][c] = (in[r][:] @ W[:][c]) * dinv[r]
// BN=true: input is pre-BN aggregate t; apply relu(t*a+shift) on load
// ---------------------------------------------------------------------------
template <int K, bool BN>
__global__ __launch_bounds__(256) void gemm_hs(const float* __restrict__ x,
                                               const float* __restrict__ ab,
                                               const float* __restrict__ W,
                                               const float* __restrict__ dinv,
                                               float* __restrict__ hs, int n) {
    __shared__ float Wl[K * NCH];
    __shared__ float Xl[32 * 32];
    __shared__ float ABl[2 * NCH];
    const int tid = threadIdx.y * 32 + threadIdx.x;
    for (int i = tid; i < K * NCH; i += 256) Wl[i] = W[i];
    if (BN && tid < 2 * NCH) ABl[tid] = ab[tid];

    const int r0 = blockIdx.x * 32;
    const int c0 = threadIdx.x;   // 0..31
    const int ry = threadIdx.y;   // 0..7
    float a[4][3] = {};

    for (int kc = 0; kc < K; kc += 32) {
        __syncthreads();
        for (int i = tid; i < 32 * 32; i += 256) {
            int row = i >> 5, kk = i & 31;
            int r = r0 + row;
            float v = (r < n) ? x[(size_t)r * K + kc + kk] : 0.0f;
            if (BN) v = fmaxf(fmaf(v, ABl[kc + kk], ABl[NCH + kc + kk]), 0.0f);
            Xl[i] = v;
        }
        __syncthreads();
#pragma unroll
        for (int kk = 0; kk < 32; ++kk) {
            float w0 = Wl[(kc + kk) * NCH + c0];
            float w1 = Wl[(kc + kk) * NCH + c0 + 32];
            float w2 = Wl[(kc + kk) * NCH + c0 + 64];
#pragma unroll
            for (int j = 0; j < 4; ++j) {
                float xv = Xl[(ry + 8 * j) * 32 + kk];
                a[j][0] = fmaf(xv, w0, a[j][0]);
                a[j][1] = fmaf(xv, w1, a[j][1]);
                a[j][2] = fmaf(xv, w2, a[j][2]);
            }
        }
    }

#pragma unroll
    for (int j = 0; j < 4; ++j) {
        int r = r0 + ry + 8 * j;
        if (r < n) {
            float dv = dinv[r];
#pragma unroll
            for (int i2 = 0; i2 < 3; ++i2)
                hs[(size_t)r * NCH + c0 + 32 * i2] = a[j][i2] * dv;
        }
    }
}

// ---------------------------------------------------------------------------
// gather aggregation: t[i] = dinv[i] * (hs[i] + sum_{src in adj[i]} hs[src])
// one wave per node, lanes 0..23 hold float4 each (96 channels)
// ---------------------------------------------------------------------------
__global__ __launch_bounds__(256) void gather_kernel(const int* __restrict__ rowptr,
                                                     const int* __restrict__ adj,
                                                     const float* __restrict__ dinv,
                                                     const float4* __restrict__ HS,
                                                     float4* __restrict__ AGG, int n) {
    int wid = (blockIdx.x * 256 + threadIdx.x) >> 6;
    int lane = threadIdx.x & 63;
    if (wid >= n || lane >= 24) return;
    int lo = rowptr[wid], hi = rowptr[wid + 1];
    float dv = dinv[wid];
    size_t l = lane;

    float4 a = HS[(size_t)wid * 24 + l];   // self term
    float4 b = make_float4(0.f, 0.f, 0.f, 0.f);
    int j = lo;
    for (; j + 1 < hi; j += 2) {
        int s0 = adj[j], s1 = adj[j + 1];
        float4 v0 = HS[(size_t)s0 * 24 + l];
        float4 v1 = HS[(size_t)s1 * 24 + l];
        a.x += v0.x; a.y += v0.y; a.z += v0.z; a.w += v0.w;
        b.x += v1.x; b.y += v1.y; b.z += v1.z; b.w += v1.w;
    }
    if (j < hi) {
        int s0 = adj[j];
        float4 v0 = HS[(size_t)s0 * 24 + l];
        a.x += v0.x; a.y += v0.y; a.z += v0.z; a.w += v0.w;
    }
    a.x = (a.x + b.x) * dv;
    a.y = (a.y + b.y) * dv;
    a.z = (a.z + b.z) * dv;
    a.w = (a.w + b.w) * dv;
    AGG[(size_t)wid * 24 + l] = a;
}

// ---------------------------------------------------------------------------
// BN column stats of t: sum, sumsq. Block = (96,4).
// ---------------------------------------------------------------------------
__global__ __launch_bounds__(384) void stats_kernel(const float* __restrict__ t,
                                                    float* __restrict__ sums, int n) {
    int c = threadIdx.x;   // 0..95
    int ry = threadIdx.y;  // 0..3
    float s1 = 0.f, s2 = 0.f;
    for (int r = blockIdx.x * 4 + ry; r < n; r += gridDim.x * 4) {
        float v = t[(size_t)r * NCH + c];
        s1 += v;
        s2 = fmaf(v, v, s2);
    }
    __shared__ float L1[4][NCH], L2[4][NCH];
    L1[ry][c] = s1;
    L2[ry][c] = s2;
    __syncthreads();
    if (ry == 0) {
        s1 = L1[0][c] + L1[1][c] + L1[2][c] + L1[3][c];
        s2 = L2[0][c] + L2[1][c] + L2[2][c] + L2[3][c];
        atomicAdd(&sums[c], s1);
        atomicAdd(&sums[NCH + c], s2);
    }
}

// a = g*rsqrt(var+eps); shift = bt - mean*a  (one tiny block)
__global__ void bnparam_kernel(const float* __restrict__ sums,
                               const float* __restrict__ g,
                               const float* __restrict__ bt,
                               float* __restrict__ ab, float n) {
    int c = threadIdx.x;
    if (c < NCH) {
        float mean = sums[c] / n;
        float var = sums[NCH + c] / n - mean * mean;
        float a = g[c] * rsqrtf(var + 1e-5f);
        ab[c] = a;
        ab[NCH + c] = bt[c] - mean * a;
    }
}

// fused BN-apply + ReLU + column-sum pool (y never materialized)
__global__ __launch_bounds__(384) void apply_pool_kernel(const float* __restrict__ t,
                                                         const float* __restrict__ ab,
                                                         float* __restrict__ pool, int n) {
    int c = threadIdx.x, ry = threadIdx.y;
    float a = ab[c], b = ab[NCH + c];
    float s = 0.f;
    for (int r = blockIdx.x * 4 + ry; r < n; r += gridDim.x * 4) {
        float v = t[(size_t)r * NCH + c];
        s += fmaxf(fmaf(v, a, b), 0.f);
    }
    __shared__ float L[4][NCH];
    L[ry][c] = s;
    __syncthreads();
    if (ry == 0) atomicAdd(&pool[c], L[0][c] + L[1][c] + L[2][c] + L[3][c]);
}

// tiny MLP head: 96 -> 128 -> 64 -> 32 -> 1, one block of 128 threads
__global__ __launch_bounds__(128) void mlp_kernel(const float* __restrict__ pool,
        const float* __restrict__ fw1, const float* __restrict__ fb1,
        const float* __restrict__ fw2, const float* __restrict__ fb2,
        const float* __restrict__ fw3, const float* __restrict__ fb3,
        const float* __restrict__ fw4, const float* __restrict__ fb4,
        float* __restrict__ out, float invn) {
    __shared__ float v[NCH], l1[128], l2[64], l3[32];
    int t = threadIdx.x;
    if (t < NCH) v[t] = pool[t] * invn;
    __syncthreads();
    {
        float a = fb1[t];
        for (int k = 0; k < NCH; ++k) a = fmaf(v[k], fw1[k * 128 + t], a);
        l1[t] = fmaxf(a, 0.f);
    }
    __syncthreads();
    if (t < 64) {
        float a = fb2[t];
        for (int k = 0; k < 128; ++k) a = fmaf(l1[k], fw2[k * 64 + t], a);
        l2[t] = fmaxf(a, 0.f);
    }
    __syncthreads();
    if (t < 32) {
        float a = fb3[t];
        for (int k = 0; k < 64; ++k) a = fmaf(l2[k], fw3[k * 32 + t], a);
        l3[t] = fmaxf(a, 0.f);
    }
    __syncthreads();
    if (t == 0) {
        float a = fb4[0];
        for (int k = 0; k < 32; ++k) a = fmaf(l3[k], fw4[k], a);
        out[0] = a;
    }
}

// ---------------------------------------------------------------------------
extern "C" void kernel_launch(void* const* d_in, const int* in_sizes, int n_in,
                              void* d_out, int out_size, void* d_ws, size_t ws_size,
                              hipStream_t stream) {
    const float* x  = (const float*)d_in[0];
    const int*  ei  = (const int*)d_in[1];
    const float* W1 = (const float*)d_in[2];
    // b1/b2/b3 cancel in BatchNorm mean subtraction — unused
    const float* W2 = (const float*)d_in[4];
    const float* W3 = (const float*)d_in[6];
    const float* g1 = (const float*)d_in[8],  *bt1 = (const float*)d_in[9];
    const float* g2 = (const float*)d_in[10], *bt2 = (const float*)d_in[11];
    const float* g3 = (const float*)d_in[12], *bt3 = (const float*)d_in[13];
    const float* fw1 = (const float*)d_in[14], *fb1 = (const float*)d_in[15];
    const float* fw2 = (const float*)d_in[16], *fb2 = (const float*)d_in[17];
    const float* fw3 = (const float*)d_in[18], *fb3 = (const float*)d_in[19];
    const float* fw4 = (const float*)d_in[20], *fb4 = (const float*)d_in[21];
    float* out = (float*)d_out;

    const int N = in_sizes[0] / 128;
    const int E = in_sizes[1] / 2;
    const size_t n96 = (size_t)N * NCH;

    // workspace layout
    float* ws    = (float*)d_ws;
    float* B0    = ws;              // ping  N*96
    float* B1    = B0 + n96;        // pong  N*96
    float* dinv  = B1 + n96;        // N
    float* sums1 = dinv + N;        // 192
    float* sums2 = sums1 + 2 * NCH; // 192
    float* sums3 = sums2 + 2 * NCH; // 192
    float* pool  = sums3 + 2 * NCH; // 96
    float* ab1   = pool + NCH;      // 192
    float* ab2   = ab1 + 2 * NCH;   // 192
    float* ab3   = ab2 + 2 * NCH;   // 192
    int*   cnt   = (int*)(ab3 + 2 * NCH);  // N (degree -> fill cursor)
    int*   rowptr= cnt + N;         // N+1
    int*   adj   = rowptr + N + 1;  // E
    int*   bsum  = adj + E;         // 256
    const int nsmall = 3 * 2 * NCH + NCH;  // sums1..3 + pool

    dim3 b96(NCH, 4);
    const int gemmGrid = (N + 31) / 32;
    const int gathGrid = (N + 3) / 4;   // 4 waves (nodes) per 256-thread block
    const int nb = (N + SCAN_TILE - 1) / SCAN_TILE;

    // ---- CSR build + dinv ----
    zero_kernel<<<(N + 255) / 256, 256, 0, stream>>>(cnt, sums1, N, nsmall);
    count_kernel<<<(E + 255) / 256, 256, 0, stream>>>(ei + E, cnt, E);
    scanA_kernel<<<nb, 256, 0, stream>>>(cnt, bsum, N);
    scanB_kernel<<<1, 256, 0, stream>>>(bsum, rowptr + N, nb);
    scanC_kernel<<<nb, 256, 0, stream>>>(cnt, bsum, rowptr, dinv, N);
    fill_kernel<<<(E + 255) / 256, 256, 0, stream>>>(ei, cnt, adj, E);

    // ---- layer 1: x(128) -> 96 ----
    gemm_hs<128, false><<<gemmGrid, dim3(32, 8), 0, stream>>>(x, nullptr, W1, dinv, B0, N);
    gather_kernel<<<gathGrid, 256, 0, stream>>>(rowptr, adj, dinv,
                                                (const float4*)B0, (float4*)B1, N);
    stats_kernel<<<512, b96, 0, stream>>>(B1, sums1, N);
    bnparam_kernel<<<1, NCH, 0, stream>>>(sums1, g1, bt1, ab1, (float)N);

    // ---- layer 2: 96 -> 96 (BN+ReLU fused into GEMM X-load) ----
    gemm_hs<96, true><<<gemmGrid, dim3(32, 8), 0, stream>>>(B1, ab1, W2, dinv, B0, N);
    gather_kernel<<<gathGrid, 256, 0, stream>>>(rowptr, adj, dinv,
                                                (const float4*)B0, (float4*)B1, N);
    stats_kernel<<<512, b96, 0, stream>>>(B1, sums2, N);
    bnparam_kernel<<<1, NCH, 0, stream>>>(sums2, g2, bt2, ab2, (float)N);

    // ---- layer 3: 96 -> 96 ----
    gemm_hs<96, true><<<gemmGrid, dim3(32, 8), 0, stream>>>(B1, ab2, W3, dinv, B0, N);
    gather_kernel<<<gathGrid, 256, 0, stream>>>(rowptr, adj, dinv,
                                                (const float4*)B0, (float4*)B1, N);
    stats_kernel<<<512, b96, 0, stream>>>(B1, sums3, N);
    bnparam_kernel<<<1, NCH, 0, stream>>>(sums3, g3, bt3, ab3, (float)N);

    // ---- fused BN-apply + pool, then MLP head ----
    apply_pool_kernel<<<512, b96, 0, stream>>>(B1, ab3, pool, N);
    mlp_kernel<<<1, 128, 0, stream>>>(pool, fw1, fb1, fw2, fb2, fw3, fb3,
                                      fw4, fb4, out, 1.0f / (float)N);
}

// Round 6
// 500.094 us; speedup vs baseline: 2.2067x; 1.1175x over previous
//
#include <hip/hip_runtime.h>
#include <math.h>

#define NCH 96        // HID_C == OUT_C == 96
#define SCAN_TILE 2048  // 256 threads x 8 elements

typedef __attribute__((ext_vector_type(8))) short short8;
typedef __attribute__((ext_vector_type(4))) float f32x4;
typedef unsigned short ushort_t;
typedef unsigned int uint_t;

// round-to-nearest-even fp32 -> bf16 bits
__device__ __forceinline__ uint_t bf16_rne(float f) {
    uint_t u = __builtin_bit_cast(uint_t, f);
    return (u + 0x7FFFu + ((u >> 16) & 1u)) >> 16;
}

__device__ __forceinline__ float4 unp(uint2 u) {
    float4 r;
    r.x = __builtin_bit_cast(float, u.x << 16);
    r.y = __builtin_bit_cast(float, u.x & 0xFFFF0000u);
    r.z = __builtin_bit_cast(float, u.y << 16);
    r.w = __builtin_bit_cast(float, u.y & 0xFFFF0000u);
    return r;
}

// ---------------------------------------------------------------------------
// zero: cnt[] = 0, small stats/pool region = 0
// ---------------------------------------------------------------------------
__global__ void zero_kernel(int* __restrict__ cnt, float* __restrict__ small,
                            int n, int nsmall) {
    int i = blockIdx.x * blockDim.x + threadIdx.x;
    if (i < n) cnt[i] = 0;
    if (i < nsmall) small[i] = 0.0f;
}

// in-degree count (int atomics, L2-resident 200 KB counter array)
__global__ void count_kernel(const int* __restrict__ dst, int* __restrict__ cnt, int E) {
    int e = blockIdx.x * blockDim.x + threadIdx.x;
    if (e < E) atomicAdd(&cnt[dst[e]], 1);
}

// ---- multi-block exclusive scan, phase A: per-block sums ----
__global__ __launch_bounds__(256) void scanA_kernel(const int* __restrict__ cnt,
                                                    int* __restrict__ bsum, int n) {
    int b = blockIdx.x, t = threadIdx.x;
    int base = b * SCAN_TILE;
    int s = 0;
    for (int i = t; i < SCAN_TILE; i += 256) {
        int idx = base + i;
        if (idx < n) s += cnt[idx];
    }
#pragma unroll
    for (int off = 32; off; off >>= 1) s += __shfl_down(s, off, 64);
    __shared__ int red[4];
    if ((t & 63) == 0) red[t >> 6] = s;
    __syncthreads();
    if (t == 0) bsum[b] = red[0] + red[1] + red[2] + red[3];
}

// ---- phase B: exclusive scan of block sums (nb <= 256); rowptrN = total ----
__global__ __launch_bounds__(256) void scanB_kernel(int* __restrict__ bsum,
                                                    int* __restrict__ rowptrN, int nb) {
    int t = threadIdx.x;
    __shared__ int ps[256];
    int v = (t < nb) ? bsum[t] : 0;
    ps[t] = v;
    __syncthreads();
    for (int off = 1; off < 256; off <<= 1) {
        int add = (t >= off) ? ps[t - off] : 0;
        __syncthreads();
        ps[t] += add;
        __syncthreads();
    }
    if (t < nb) bsum[t] = ps[t] - v;     // exclusive prefix
    if (t == nb - 1) rowptrN[0] = ps[t]; // total = E
}

// ---- phase C: block-local scan, write rowptr / fill-cursor / dinv ----
__global__ __launch_bounds__(256) void scanC_kernel(int* __restrict__ cnt,
                                                    const int* __restrict__ bsum,
                                                    int* __restrict__ rowptr,
                                                    float* __restrict__ dinv, int n) {
    int b = blockIdx.x, t = threadIdx.x;
    int base = b * SCAN_TILE + t * 8;
    int c[8];
    int s = 0;
#pragma unroll
    for (int j = 0; j < 8; ++j) {
        int idx = base + j;
        c[j] = (idx < n) ? cnt[idx] : 0;
        s += c[j];
    }
    __shared__ int ps[256];
    ps[t] = s;
    __syncthreads();
    for (int off = 1; off < 256; off <<= 1) {
        int add = (t >= off) ? ps[t - off] : 0;
        __syncthreads();
        ps[t] += add;
        __syncthreads();
    }
    int run = bsum[b] + ps[t] - s;
#pragma unroll
    for (int j = 0; j < 8; ++j) {
        int idx = base + j;
        if (idx < n) {
            rowptr[idx] = run;
            cnt[idx] = run;                       // fill cursor
            dinv[idx] = rsqrtf((float)(c[j] + 1)); // self-loop degree
            run += c[j];
        }
    }
}

// adj fill via int atomics on the fill cursors
__global__ void fill_kernel(const int* __restrict__ ei, int* __restrict__ fill,
                            int* __restrict__ adj, int E) {
    int e = blockIdx.x * blockDim.x + threadIdx.x;
    if (e < E) {
        int s = ei[e];
        int pos = atomicAdd(&fill[ei[E + e]], 1);
        adj[pos] = s;
    }
}

// ---------------------------------------------------------------------------
// MFMA GEMM (split-bf16, fp32-grade): hs[r][c] = bf16((in[r][:]@W[:][c]) * dinv[r])
// BN=true: input is pre-BN aggregate t; apply relu(t*a+shift) on A-load.
// Block = 256 threads (4 waves); wave computes 32 rows x 96 cols
// via 2x6 tiles of v_mfma_f32_16x16x32_bf16, 3 MFMAs per tile (hi*hi,lo*hi,hi*lo).
// Fragment layout: A row=l&15, k=(l>>4)*8+i;  B col=l&15, same k;
// C/D col=l&15, row=(l>>4)*4+reg  (m89/m97-verified layouts).
// ---------------------------------------------------------------------------
template <int K, bool BN>
__global__ __launch_bounds__(256) void gemm_mfma(const float* __restrict__ x,
                                                 const float* __restrict__ ab,
                                                 const float* __restrict__ W,
                                                 const float* __restrict__ dinv,
                                                 ushort_t* __restrict__ hs, int n) {
    constexpr int NKS = K / 32;
    constexpr int NFR = NKS * 6 * 512;   // frag elems per (hi|lo) array
    __shared__ short BH[NFR];
    __shared__ short BL[NFR];
    __shared__ float ABl[2 * NCH];

    const int tid = threadIdx.x;
    // ---- build W fragments (hi/lo split) in LDS ----
    for (int idx = tid; idx < NFR; idx += 256) {
        int i  = idx & 7;
        int l2 = (idx >> 3) & 63;
        int r  = idx >> 9;          // = ks*6 + ct
        int ct = r % 6;
        int ks = r / 6;
        int k   = ks * 32 + ((l2 >> 4) << 3) + i;
        int col = ct * 16 + (l2 & 15);
        float w = W[k * NCH + col];
        uint_t hb = bf16_rne(w);
        float hf = __builtin_bit_cast(float, hb << 16);
        uint_t lb = bf16_rne(w - hf);
        BH[idx] = (short)hb;
        BL[idx] = (short)lb;
    }
    if constexpr (BN) {
        if (tid < 2 * NCH) ABl[tid] = ab[tid];
    }
    __syncthreads();

    const int l  = tid & 63;
    const int wv = tid >> 6;
    const int r0 = blockIdx.x * 128 + wv * 32;
    const int klo = (l >> 4) << 3;   // 0,8,16,24

    f32x4 acc[2][6] = {};

    for (int ks = 0; ks < NKS; ++ks) {
        float av[8], bv[8];
        if constexpr (BN) {
            int kb = ks * 32 + klo;
#pragma unroll
            for (int i = 0; i < 8; ++i) { av[i] = ABl[kb + i]; bv[i] = ABl[NCH + kb + i]; }
        }
        short8 Ah[2], Al[2];
#pragma unroll
        for (int rt = 0; rt < 2; ++rt) {
            int rg = r0 + rt * 16 + (l & 15);
            rg = rg < n ? rg : n - 1;               // clamp (discarded at store)
            const float* px = x + (size_t)rg * K + ks * 32 + klo;
            float4 f0 = *(const float4*)px;
            float4 f1 = *(const float4*)(px + 4);
            float vv[8] = {f0.x, f0.y, f0.z, f0.w, f1.x, f1.y, f1.z, f1.w};
#pragma unroll
            for (int i = 0; i < 8; ++i) {
                float v = vv[i];
                if constexpr (BN) v = fmaxf(fmaf(v, av[i], bv[i]), 0.0f);
                uint_t hb = bf16_rne(v);
                float hf = __builtin_bit_cast(float, hb << 16);
                uint_t lb = bf16_rne(v - hf);
                Ah[rt][i] = (short)hb;
                Al[rt][i] = (short)lb;
            }
        }
#pragma unroll
        for (int ct = 0; ct < 6; ++ct) {
            int off = ((ks * 6 + ct) << 9) + (l << 3);
            short8 bh = *(const short8*)&BH[off];
            short8 bl = *(const short8*)&BL[off];
#pragma unroll
            for (int rt = 0; rt < 2; ++rt) {
                acc[rt][ct] = __builtin_amdgcn_mfma_f32_16x16x32_bf16(Ah[rt], bh, acc[rt][ct], 0, 0, 0);
                acc[rt][ct] = __builtin_amdgcn_mfma_f32_16x16x32_bf16(Al[rt], bh, acc[rt][ct], 0, 0, 0);
                acc[rt][ct] = __builtin_amdgcn_mfma_f32_16x16x32_bf16(Ah[rt], bl, acc[rt][ct], 0, 0, 0);
            }
        }
    }

    // ---- epilogue: *dinv, ->bf16, store ----
#pragma unroll
    for (int rt = 0; rt < 2; ++rt) {
#pragma unroll
        for (int i = 0; i < 4; ++i) {
            int row = r0 + rt * 16 + ((l >> 4) << 2) + i;
            if (row < n) {
                float dv = dinv[row];
#pragma unroll
                for (int ct = 0; ct < 6; ++ct) {
                    float v = acc[rt][ct][i] * dv;
                    hs[(size_t)row * NCH + ct * 16 + (l & 15)] = (ushort_t)bf16_rne(v);
                }
            }
        }
    }
}

// ---------------------------------------------------------------------------
// gather aggregation: t[i] = dinv[i] * (hs[i] + sum_{src in adj[i]} hs[src])
// hs is bf16 (192 B/row); one wave per node, lanes 0..23 read uint2 (4 ch each)
// ---------------------------------------------------------------------------
__global__ __launch_bounds__(256) void gather_kernel(const int* __restrict__ rowptr,
                                                     const int* __restrict__ adj,
                                                     const float* __restrict__ dinv,
                                                     const ushort_t* __restrict__ HS,
                                                     float* __restrict__ AGG, int n) {
    int wid = (blockIdx.x * 256 + threadIdx.x) >> 6;
    int lane = threadIdx.x & 63;
    if (wid >= n || lane >= 24) return;
    int lo = rowptr[wid], hi = rowptr[wid + 1];
    float dv = dinv[wid];
    const uint_t* HSu = (const uint_t*)HS;
    const int l2 = lane * 2;

    float4 a = unp(*(const uint2*)(HSu + (size_t)wid * 48 + l2));   // self term
    float4 b = make_float4(0.f, 0.f, 0.f, 0.f);
    int j = lo;
    for (; j + 1 < hi; j += 2) {
        int s0 = adj[j], s1 = adj[j + 1];
        float4 v0 = unp(*(const uint2*)(HSu + (size_t)s0 * 48 + l2));
        float4 v1 = unp(*(const uint2*)(HSu + (size_t)s1 * 48 + l2));
        a.x += v0.x; a.y += v0.y; a.z += v0.z; a.w += v0.w;
        b.x += v1.x; b.y += v1.y; b.z += v1.z; b.w += v1.w;
    }
    if (j < hi) {
        int s0 = adj[j];
        float4 v0 = unp(*(const uint2*)(HSu + (size_t)s0 * 48 + l2));
        a.x += v0.x; a.y += v0.y; a.z += v0.z; a.w += v0.w;
    }
    a.x = (a.x + b.x) * dv;
    a.y = (a.y + b.y) * dv;
    a.z = (a.z + b.z) * dv;
    a.w = (a.w + b.w) * dv;
    ((float4*)(AGG + (size_t)wid * NCH))[lane] = a;
}

// ---------------------------------------------------------------------------
// BN column stats of t: sum, sumsq. Block = (96,4).
// ---------------------------------------------------------------------------
__global__ __launch_bounds__(384) void stats_kernel(const float* __restrict__ t,
                                                    float* __restrict__ sums, int n) {
    int c = threadIdx.x;   // 0..95
    int ry = threadIdx.y;  // 0..3
    float s1 = 0.f, s2 = 0.f;
    for (int r = blockIdx.x * 4 + ry; r < n; r += gridDim.x * 4) {
        float v = t[(size_t)r * NCH + c];
        s1 += v;
        s2 = fmaf(v, v, s2);
    }
    __shared__ float L1[4][NCH], L2[4][NCH];
    L1[ry][c] = s1;
    L2[ry][c] = s2;
    __syncthreads();
    if (ry == 0) {
        s1 = L1[0][c] + L1[1][c] + L1[2][c] + L1[3][c];
        s2 = L2[0][c] + L2[1][c] + L2[2][c] + L2[3][c];
        atomicAdd(&sums[c], s1);
        atomicAdd(&sums[NCH + c], s2);
    }
}

// a = g*rsqrt(var+eps); shift = bt - mean*a  (one tiny block)
__global__ void bnparam_kernel(const float* __restrict__ sums,
                               const float* __restrict__ g,
                               const float* __restrict__ bt,
                               float* __restrict__ ab, float n) {
    int c = threadIdx.x;
    if (c < NCH) {
        float mean = sums[c] / n;
        float var = sums[NCH + c] / n - mean * mean;
        float a = g[c] * rsqrtf(var + 1e-5f);
        ab[c] = a;
        ab[NCH + c] = bt[c] - mean * a;
    }
}

// fused BN-apply + ReLU + column-sum pool (y never materialized)
__global__ __launch_bounds__(384) void apply_pool_kernel(const float* __restrict__ t,
                                                         const float* __restrict__ ab,
                                                         float* __restrict__ pool, int n) {
    int c = threadIdx.x, ry = threadIdx.y;
    float a = ab[c], b = ab[NCH + c];
    float s = 0.f;
    for (int r = blockIdx.x * 4 + ry; r < n; r += gridDim.x * 4) {
        float v = t[(size_t)r * NCH + c];
        s += fmaxf(fmaf(v, a, b), 0.f);
    }
    __shared__ float L[4][NCH];
    L[ry][c] = s;
    __syncthreads();
    if (ry == 0) atomicAdd(&pool[c], L[0][c] + L[1][c] + L[2][c] + L[3][c]);
}

// tiny MLP head: 96 -> 128 -> 64 -> 32 -> 1, one block of 128 threads
__global__ __launch_bounds__(128) void mlp_kernel(const float* __restrict__ pool,
        const float* __restrict__ fw1, const float* __restrict__ fb1,
        const float* __restrict__ fw2, const float* __restrict__ fb2,
        const float* __restrict__ fw3, const float* __restrict__ fb3,
        const float* __restrict__ fw4, const float* __restrict__ fb4,
        float* __restrict__ out, float invn) {
    __shared__ float v[NCH], l1[128], l2[64], l3[32];
    int t = threadIdx.x;
    if (t < NCH) v[t] = pool[t] * invn;
    __syncthreads();
    {
        float a = fb1[t];
        for (int k = 0; k < NCH; ++k) a = fmaf(v[k], fw1[k * 128 + t], a);
        l1[t] = fmaxf(a, 0.f);
    }
    __syncthreads();
    if (t < 64) {
        float a = fb2[t];
        for (int k = 0; k < 128; ++k) a = fmaf(l1[k], fw2[k * 64 + t], a);
        l2[t] = fmaxf(a, 0.f);
    }
    __syncthreads();
    if (t < 32) {
        float a = fb3[t];
        for (int k = 0; k < 64; ++k) a = fmaf(l2[k], fw3[k * 32 + t], a);
        l3[t] = fmaxf(a, 0.f);
    }
    __syncthreads();
    if (t == 0) {
        float a = fb4[0];
        for (int k = 0; k < 32; ++k) a = fmaf(l3[k], fw4[k], a);
        out[0] = a;
    }
}

// ---------------------------------------------------------------------------
extern "C" void kernel_launch(void* const* d_in, const int* in_sizes, int n_in,
                              void* d_out, int out_size, void* d_ws, size_t ws_size,
                              hipStream_t stream) {
    const float* x  = (const float*)d_in[0];
    const int*  ei  = (const int*)d_in[1];
    const float* W1 = (const float*)d_in[2];
    // b1/b2/b3 cancel in BatchNorm mean subtraction — unused
    const float* W2 = (const float*)d_in[4];
    const float* W3 = (const float*)d_in[6];
    const float* g1 = (const float*)d_in[8],  *bt1 = (const float*)d_in[9];
    const float* g2 = (const float*)d_in[10], *bt2 = (const float*)d_in[11];
    const float* g3 = (const float*)d_in[12], *bt3 = (const float*)d_in[13];
    const float* fw1 = (const float*)d_in[14], *fb1 = (const float*)d_in[15];
    const float* fw2 = (const float*)d_in[16], *fb2 = (const float*)d_in[17];
    const float* fw3 = (const float*)d_in[18], *fb3 = (const float*)d_in[19];
    const float* fw4 = (const float*)d_in[20], *fb4 = (const float*)d_in[21];
    float* out = (float*)d_out;

    const int N = in_sizes[0] / 128;
    const int E = in_sizes[1] / 2;
    const size_t n96 = (size_t)N * NCH;

    // workspace layout
    float* ws    = (float*)d_ws;
    float* T     = ws;                       // fp32 aggregate     N*96
    ushort_t* HSB = (ushort_t*)(T + n96);    // bf16 hs            N*96 (n96/2 floats)
    float* dinv  = T + n96 + n96 / 2;        // N
    float* sums1 = dinv + N;        // 192
    float* sums2 = sums1 + 2 * NCH; // 192
    float* sums3 = sums2 + 2 * NCH; // 192
    float* pool  = sums3 + 2 * NCH; // 96
    float* ab1   = pool + NCH;      // 192
    float* ab2   = ab1 + 2 * NCH;   // 192
    float* ab3   = ab2 + 2 * NCH;   // 192
    int*   cnt   = (int*)(ab3 + 2 * NCH);  // N (degree -> fill cursor)
    int*   rowptr= cnt + N;         // N+1
    int*   adj   = rowptr + N + 1;  // E
    int*   bsum  = adj + E;         // 256
    const int nsmall = 3 * 2 * NCH + NCH;  // sums1..3 + pool

    dim3 b96(NCH, 4);
    const int gemmGrid = (N + 127) / 128;
    const int gathGrid = (N + 3) / 4;   // 4 waves (nodes) per 256-thread block
    const int nb = (N + SCAN_TILE - 1) / SCAN_TILE;

    // ---- CSR build + dinv ----
    zero_kernel<<<(N + 255) / 256, 256, 0, stream>>>(cnt, sums1, N, nsmall);
    count_kernel<<<(E + 255) / 256, 256, 0, stream>>>(ei + E, cnt, E);
    scanA_kernel<<<nb, 256, 0, stream>>>(cnt, bsum, N);
    scanB_kernel<<<1, 256, 0, stream>>>(bsum, rowptr + N, nb);
    scanC_kernel<<<nb, 256, 0, stream>>>(cnt, bsum, rowptr, dinv, N);
    fill_kernel<<<(E + 255) / 256, 256, 0, stream>>>(ei, cnt, adj, E);

    // ---- layer 1: x(128) -> 96 ----
    gemm_mfma<128, false><<<gemmGrid, 256, 0, stream>>>(x, nullptr, W1, dinv, HSB, N);
    gather_kernel<<<gathGrid, 256, 0, stream>>>(rowptr, adj, dinv, HSB, T, N);
    stats_kernel<<<512, b96, 0, stream>>>(T, sums1, N);
    bnparam_kernel<<<1, NCH, 0, stream>>>(sums1, g1, bt1, ab1, (float)N);

    // ---- layer 2: 96 -> 96 (BN+ReLU fused into GEMM A-load) ----
    gemm_mfma<96, true><<<gemmGrid, 256, 0, stream>>>(T, ab1, W2, dinv, HSB, N);
    gather_kernel<<<gathGrid, 256, 0, stream>>>(rowptr, adj, dinv, HSB, T, N);
    stats_kernel<<<512, b96, 0, stream>>>(T, sums2, N);
    bnparam_kernel<<<1, NCH, 0, stream>>>(sums2, g2, bt2, ab2, (float)N);

    // ---- layer 3: 96 -> 96 ----
    gemm_mfma<96, true><<<gemmGrid, 256, 0, stream>>>(T, ab2, W3, dinv, HSB, N);
    gather_kernel<<<gathGrid, 256, 0, stream>>>(rowptr, adj, dinv, HSB, T, N);
    stats_kernel<<<512, b96, 0, stream>>>(T, sums3, N);
    bnparam_kernel<<<1, NCH, 0, stream>>>(sums3, g3, bt3, ab3, (float)N);

    // ---- fused BN-apply + pool, then MLP head ----
    apply_pool_kernel<<<512, b96, 0, stream>>>(T, ab3, pool, N);
    mlp_kernel<<<1, 128, 0, stream>>>(pool, fw1, fb1, fw2, fb2, fw3, fb3,
                                      fw4, fb4, out, 1.0f / (float)N);
}